// Round 4
// baseline (264.226 us; speedup 1.0000x reference)
//
#include <hip/hip_runtime.h>
#include <hip/hip_bf16.h>

// B=8192 rows, N=4096 omegas/row, W=1000 bins, L=101 Legendre terms.
// Exact simplifications (carried from verified r3 kernel):
//   * pdf normalization cancels in grad/pdf -> skipped
//   * sigma<=0.6 rows are pure elementwise -omega/sigma^2
//   * series terms beyond l=16 underflow for sigma>0.6 -> fixed L=17 unroll
// Round-4 structure: SPLIT. Kernel A builds all pdf tables (32 MB ws,
// L2/L3-resident); kernel B is a uniform, minimal-critical-path streamer:
// stage 4KB table (1 v4f load + 1 ds_write_b128 per thread) -> barrier ->
// gather. Pad handling moved from table layout into clamp arithmetic so
// all stores/loads are aligned dwordx4:
//   left  = pdf_pad[idx]   == p[max(idx-1,0)]
//   right = pdf_pad[idx+1] == p[idx>=1000 ? 998 : idx]   (idx clamped <=1000)
// Fallback (ws too small): round-3-verified combined kernel.

#define L_TERMS 101
#define W_BINS 1000
#define N_COLS 4096
#define TPB 256
#define TRANS_STRIDE 1024   // padded transpose row stride
#define TAB_STRIDE 1024     // floats per pdf-table row in workspace
#define PAD_W 1004          // (fallback kernel only)
#define GRAD_T 0.6f
#define L_FIX 17            // fixed term count, exact for sigma > 0.6

typedef float v4f __attribute__((ext_vector_type(4)));

// ---------------------------------------------------------------------------
// Transpose sine_terms [1000][101] -> sine_t [101][1024] (padded)
__global__ __launch_bounds__(128) void transpose_sine(
    const float* __restrict__ sine, float* __restrict__ sine_t) {
  int w = blockIdx.x;   // 0..999
  int t = threadIdx.x;  // 0..127
  if (t < L_TERMS) sine_t[(size_t)t * TRANS_STRIDE + w] = sine[(size_t)w * L_TERMS + t];
}

// ---------------------------------------------------------------------------
// Kernel A: per series-row pdf table -> tabs[b][0..999] (aligned stores).
__global__ __launch_bounds__(TPB, 6) void build_tables(
    const float* __restrict__ sigmas,
    const float* __restrict__ sine_t,   // [101][1024]
    float* __restrict__ tabs) {         // [B][1024]
  const int b = blockIdx.x;
  const float s = sigmas[b];
  if (s <= GRAD_T) return;              // gaussian row: no table needed

  const int tid = threadIdx.x;
  const int w0 = tid * 4;
  if (w0 >= W_BINS) return;

  float e[L_FIX];
  const float ns2 = -0.5f * s * s;
#pragma unroll
  for (int l = 0; l < L_FIX; ++l)
    e[l] = __expf(ns2 * (float)(l * (l + 1)));

  float acc[4] = {0.0f, 0.0f, 0.0f, 0.0f};
#pragma unroll
  for (int l = 0; l < L_FIX; ++l) {
    v4f sv = *(const v4f*)(sine_t + (size_t)l * TRANS_STRIDE + w0);
    acc[0] = fmaf(e[l], sv.x, acc[0]);
    acc[1] = fmaf(e[l], sv.y, acc[1]);
    acc[2] = fmaf(e[l], sv.z, acc[2]);
    acc[3] = fmaf(e[l], sv.w, acc[3]);
  }
  v4f r = {acc[0], acc[1], acc[2], acc[3]};
  *(v4f*)(tabs + (size_t)b * TAB_STRIDE + w0) = r;   // cached store: B reads it next
}

// ---------------------------------------------------------------------------
// Kernel B: uniform streamer. Stage 4KB table -> LDS, gather, store.
__global__ __launch_bounds__(TPB, 8) void igso3_gather(
    const float* __restrict__ sigmas,
    const float* __restrict__ omegas,
    const float* __restrict__ omega_grid,
    const float* __restrict__ tabs,
    float* __restrict__ out) {
  __shared__ float s_tab[TAB_STRIDE];   // p[0..999]; [1000..1023] garbage, never read

  const int tid = threadIdx.x;
  const int b = blockIdx.x;
  const float s = sigmas[b];

  const v4f* __restrict__ om4 = (const v4f*)(omegas + (size_t)b * N_COLS);
  v4f* __restrict__ out4 = (v4f*)(out + (size_t)b * N_COLS);

  // Issue the table load FIRST (oldest in vmem queue), then the row loads:
  // both latencies overlap; single barrier drains everything.
  v4f tv;
  if (s > GRAD_T)
    tv = *(const v4f*)(tabs + (size_t)b * TAB_STRIDE + tid * 4);  // tid*4<1024

  v4f om[4];
#pragma unroll
  for (int k = 0; k < 4; ++k) om[k] = om4[k * TPB + tid];

  const float bw = omega_grid[1] - omega_grid[0];
  const float inv_bw = 1.0f / bw;

  if (s <= GRAD_T) {
    const float inv_s2 = __builtin_amdgcn_rcpf(s * s);
#pragma unroll
    for (int k = 0; k < 4; ++k) {
      v4f r = om[k] * (-inv_s2);
      __builtin_nontemporal_store(r, &out4[k * TPB + tid]);
    }
    return;   // block-uniform: barrier below never executed in this block
  }

  *(v4f*)(s_tab + tid * 4) = tv;        // linear b128 write, conflict-free
  __syncthreads();

#pragma unroll
  for (int k = 0; k < 4; ++k) {
    float o[4] = {om[k].x, om[k].y, om[k].z, om[k].w};
    float rv[4];
#pragma unroll
    for (int j = 0; j < 4; ++j) {
      // omega >= 0 -> int-cast == floor; idx in [0,1000]
      int idx = (int)fmaf(o[j], inv_bw, 0.5f);
      idx = min(idx, 1000);
      float shift = fmaf(-((float)idx + 0.5f), bw, o[j]);
      int il = max(idx - 1, 0);               // pdf_pad[idx]
      int ir = (idx >= 1000) ? 998 : idx;     // pdf_pad[idx+1]
      float left  = s_tab[il];
      float right = s_tab[ir];
      float grad = (right - left) * inv_bw;
      float accu = fmaf(shift, grad, left);
      rv[j] = grad * __builtin_amdgcn_rcpf(accu);
    }
    v4f res = {rv[0], rv[1], rv[2], rv[3]};
    __builtin_nontemporal_store(res, &out4[k * TPB + tid]);
  }
}

// ---------------------------------------------------------------------------
// Fallback: round-3-verified combined kernel (used when ws is small).
template <bool TRANS>
__global__ __launch_bounds__(TPB, 6) void igso3_main(
    const float* __restrict__ sigmas,
    const float* __restrict__ omegas,
    const float* __restrict__ omega_grid,
    const float* __restrict__ sine_src,  // TRANS ? [101][1024] : [1000][101]
    float* __restrict__ out) {
  __shared__ float s_pdf[PAD_W];

  const int tid = threadIdx.x;
  const int b = blockIdx.x;

  const v4f* __restrict__ om4 = (const v4f*)(omegas + (size_t)b * N_COLS);
  v4f* __restrict__ out4 = (v4f*)(out + (size_t)b * N_COLS);

  v4f om[4];
#pragma unroll
  for (int k = 0; k < 4; ++k) om[k] = om4[k * TPB + tid];

  const float s = sigmas[b];
  const float bw = omega_grid[1] - omega_grid[0];
  const float inv_bw = 1.0f / bw;

  if (s <= GRAD_T) {
    const float inv_s2 = __builtin_amdgcn_rcpf(s * s);
#pragma unroll
    for (int k = 0; k < 4; ++k) {
      v4f r = om[k] * (-inv_s2);
      __builtin_nontemporal_store(r, &out4[k * TPB + tid]);
    }
    return;
  }

  float e[L_FIX];
  const float ns2 = -0.5f * s * s;
#pragma unroll
  for (int l = 0; l < L_FIX; ++l) {
    float ev = __expf(ns2 * (float)(l * (l + 1)));
    e[l] = __int_as_float(__builtin_amdgcn_readfirstlane(__float_as_int(ev)));
  }

  const int w0 = tid * 4;
  float acc[4] = {0.0f, 0.0f, 0.0f, 0.0f};
  if (TRANS) {
#pragma unroll
    for (int l = 0; l < L_FIX; ++l) {
      v4f sv = *(const v4f*)(sine_src + (size_t)l * TRANS_STRIDE + w0);
      acc[0] = fmaf(e[l], sv.x, acc[0]);
      acc[1] = fmaf(e[l], sv.y, acc[1]);
      acc[2] = fmaf(e[l], sv.z, acc[2]);
      acc[3] = fmaf(e[l], sv.w, acc[3]);
    }
  } else if (w0 < W_BINS) {
#pragma unroll
    for (int l = 0; l < L_FIX; ++l) {
#pragma unroll
      for (int j = 0; j < 4; ++j)
        acc[j] = fmaf(e[l], sine_src[(size_t)(w0 + j) * L_TERMS + l], acc[j]);
    }
  }
  if (w0 < W_BINS) {
#pragma unroll
    for (int j = 0; j < 4; ++j) s_pdf[w0 + 1 + j] = acc[j];
    if (tid == 0) s_pdf[0] = acc[0];
    if (w0 == 996) s_pdf[1001] = acc[2];
  }
  __syncthreads();

#pragma unroll
  for (int k = 0; k < 4; ++k) {
    float o[4] = {om[k].x, om[k].y, om[k].z, om[k].w};
    float rv[4];
#pragma unroll
    for (int j = 0; j < 4; ++j) {
      int idx = (int)fmaf(o[j], inv_bw, 0.5f);
      idx = min(idx, 1000);
      float shift = fmaf(-((float)idx + 0.5f), bw, o[j]);
      float left  = s_pdf[idx];
      float right = s_pdf[idx + 1];
      float grad = (right - left) * inv_bw;
      float accu = fmaf(shift, grad, left);
      rv[j] = grad * __builtin_amdgcn_rcpf(accu);
    }
    v4f res = {rv[0], rv[1], rv[2], rv[3]};
    __builtin_nontemporal_store(res, &out4[k * TPB + tid]);
  }
}

// ---------------------------------------------------------------------------
extern "C" void kernel_launch(void* const* d_in, const int* in_sizes, int n_in,
                              void* d_out, int out_size, void* d_ws, size_t ws_size,
                              hipStream_t stream) {
  const float* sigmas     = (const float*)d_in[0];
  const float* omegas     = (const float*)d_in[1];
  const float* omega_grid = (const float*)d_in[2];
  // d_in[3] = ls (unused)
  const float* sine_terms = (const float*)d_in[4];
  float* out = (float*)d_out;

  const int B = in_sizes[0];  // 8192 -> one block per row

  const size_t tab_bytes   = (size_t)B * TAB_STRIDE * sizeof(float);      // 32 MB
  const size_t trans_bytes = (size_t)L_TERMS * TRANS_STRIDE * sizeof(float); // 404 KB

  if (ws_size >= tab_bytes + trans_bytes) {
    float* tabs   = (float*)d_ws;
    float* sine_t = (float*)((char*)d_ws + tab_bytes);
    transpose_sine<<<W_BINS, 128, 0, stream>>>(sine_terms, sine_t);
    build_tables<<<B, TPB, 0, stream>>>(sigmas, sine_t, tabs);
    igso3_gather<<<B, TPB, 0, stream>>>(sigmas, omegas, omega_grid, tabs, out);
  } else if (ws_size >= trans_bytes) {
    transpose_sine<<<W_BINS, 128, 0, stream>>>(sine_terms, (float*)d_ws);
    igso3_main<true><<<B, TPB, 0, stream>>>(sigmas, omegas, omega_grid,
                                            (const float*)d_ws, out);
  } else {
    igso3_main<false><<<B, TPB, 0, stream>>>(sigmas, omegas, omega_grid,
                                             sine_terms, out);
  }
}